// Round 1
// 852.252 us; speedup vs baseline: 1.4863x; 1.4863x over previous
//
#include <hip/hip_runtime.h>
#include <math.h>

#define Tdim 2048
#define HIDd 1024
#define NHd 16
#define NCOL 4096         // NH*16*16
#define Cn 64             // chunks per sequence
#define Ln 32             // chunk length (Cn*Ln == Tdim)
#define LSTR 40           // f16 elems per LDS row (80 B): bank-friendly pad (gemm2)
#define KCAT 3072         // concatenated K: [Ah|Ah/32|Al*32] x [Bh|Bl*32|Bh/32]
#define KB 6144           // KCAT * sizeof(_Float16)

typedef _Float16 f16x4  __attribute__((ext_vector_type(4)));
typedef _Float16 f16x8  __attribute__((ext_vector_type(8)));
typedef float    f32x4  __attribute__((ext_vector_type(4)));

typedef __attribute__((address_space(1))) void gvoid_t;
typedef __attribute__((address_space(3))) void lvoid_t;

// ---------------- hs (rows x 1024 fp32) -> A_cat (rows x 3072 f16) ------------------------
// planes: [0:1024)=Ah, [1024:2048)=Ah/32 (exact), [2048:3072)=(hs-Ah)*32 (exact scaling)
__global__ __launch_bounds__(256) void conv_A_kernel(const float* __restrict__ hs,
                                                     _Float16* __restrict__ Ac)
{
    const size_t i = ((size_t)blockIdx.x * 256 + threadIdx.x) * 8;
    const size_t r = i >> 10, k = i & 1023;
    const float4 x0 = *(const float4*)(hs + i);
    const float4 x1 = *(const float4*)(hs + i + 4);
    const float v[8] = {x0.x, x0.y, x0.z, x0.w, x1.x, x1.y, x1.z, x1.w};
    f16x8 h, hm, l;
#pragma unroll
    for (int j = 0; j < 8; ++j) {
        const _Float16 hh = (_Float16)v[j];
        h[j]  = hh;
        hm[j] = (_Float16)(v[j] * 0.03125f);          // == hh/32 exactly (pow2 scale)
        l[j]  = (_Float16)((v[j] - (float)hh) * 32.0f);
    }
    _Float16* o = Ac + r * KCAT + k;
    *(f16x8*)(o)        = h;
    *(f16x8*)(o + 1024) = hm;
    *(f16x8*)(o + 2048) = l;
}

// ---------------- W_mat (1024 x 4096 fp32) -> B_cat (4096 x 3072 f16) ---------------------
__global__ __launch_bounds__(256) void conv_B_kernel(const float* __restrict__ W,
                                                     _Float16* __restrict__ Bc)
{
    __shared__ float t[32][33];
    const int tx = threadIdx.x & 31, ty = threadIdx.x >> 5;   // ty 0..7
    const int n0 = blockIdx.x * 32, k0 = blockIdx.y * 32;
#pragma unroll
    for (int i = 0; i < 4; ++i)
        t[ty + i * 8][tx] = W[(size_t)(k0 + ty + i * 8) * NCOL + n0 + tx];
    __syncthreads();
#pragma unroll
    for (int i = 0; i < 4; ++i) {
        const float w = t[tx][ty + i * 8];
        const _Float16 h = (_Float16)w;
        const size_t o = (size_t)(n0 + ty + i * 8) * KCAT + k0 + tx;
        Bc[o]        = h;
        Bc[o + 1024] = (_Float16)((w - (float)h) * 32.0f);
        Bc[o + 2048] = (_Float16)((float)h * 0.03125f);   // exact
    }
}

// ---------------- W_out (512 x 1024 fp32) -> W2T (1024 x 512 fp16) ------------------------
__global__ __launch_bounds__(256) void conv_W2T_kernel(const float* __restrict__ W,
                                                       _Float16* __restrict__ WT)
{
    __shared__ float t[32][33];
    const int tx = threadIdx.x & 31, ty = threadIdx.x >> 5;
    const int n0 = blockIdx.x * 32, k0 = blockIdx.y * 32;
#pragma unroll
    for (int i = 0; i < 4; ++i)
        t[ty + i * 8][tx] = W[(size_t)(k0 + ty + i * 8) * 1024 + n0 + tx];
    __syncthreads();
#pragma unroll
    for (int i = 0; i < 4; ++i)
        WT[(size_t)(n0 + ty + i * 8) * 512 + k0 + tx] = (_Float16)t[tx][ty + i * 8];
}

// ---------------- GEMM1: 256x256 tile, BK=64, 8-phase counted-vmcnt pipeline --------------
// m = hs @ W_mat + b_mat via single-accumulator K-concat f16 GEMM (K=3072), scattered out.
// LDS: 2 buffers x (A 256x64 + B 256x64) f16 = 128 KiB, XOR-swizzle col^=(row&7)<<4 applied
// on the global SOURCE of global_load_lds (dest linear) and on every ds_read -> conflict-free.

#define MFMA_PHASE(CPH) \
    _Pragma("unroll") \
    for (int m2_ = 0; m2_ < 2; ++m2_) { \
        _Pragma("unroll") \
        for (int nt_ = 0; nt_ < 4; ++nt_) { \
            acc[(CPH)*2 + m2_][nt_] = __builtin_amdgcn_mfma_f32_16x16x32_f16(af[m2_][0], bf[nt_][0], acc[(CPH)*2 + m2_][nt_], 0, 0, 0); \
            acc[(CPH)*2 + m2_][nt_] = __builtin_amdgcn_mfma_f32_16x16x32_f16(af[m2_][1], bf[nt_][1], acc[(CPH)*2 + m2_][nt_], 0, 0, 0); \
        } \
    }

#define PHASE(BUF, CPH, STAGE_EXPR, DOGATE) do { \
    af[0][0] = readA(BUF, (CPH)*2,     0); \
    af[0][1] = readA(BUF, (CPH)*2,     1); \
    af[1][0] = readA(BUF, (CPH)*2 + 1, 0); \
    af[1][1] = readA(BUF, (CPH)*2 + 1, 1); \
    if ((CPH) == 0) { \
        _Pragma("unroll") \
        for (int nt_ = 0; nt_ < 4; ++nt_) { bf[nt_][0] = readB(BUF, nt_, 0); bf[nt_][1] = readB(BUF, nt_, 1); } \
    } \
    STAGE_EXPR; \
    asm volatile("s_barrier" ::: "memory"); \
    asm volatile("s_waitcnt lgkmcnt(0)" ::: "memory"); \
    __builtin_amdgcn_sched_barrier(0); \
    __builtin_amdgcn_s_setprio(1); \
    MFMA_PHASE(CPH) \
    __builtin_amdgcn_s_setprio(0); \
    if (DOGATE) { \
        if (notlast) asm volatile("s_waitcnt vmcnt(6)" ::: "memory"); \
        else         asm volatile("s_waitcnt vmcnt(0)" ::: "memory"); \
    } \
    asm volatile("s_barrier" ::: "memory"); \
} while (0)

__global__ __launch_bounds__(512, 2) void gemm1_8ph(const _Float16* __restrict__ A,
                                                    const _Float16* __restrict__ B,
                                                    const float* __restrict__ bias,
                                                    float* __restrict__ Mout)
{
    __shared__ __align__(16) _Float16 sA[2][256 * 64];
    __shared__ __align__(16) _Float16 sB[2][256 * 64];
    const int tid = threadIdx.x;
    const int lane = tid & 63;
    const int wid = tid >> 6;
    const int wm = wid >> 2, wn = wid & 3;        // wave grid 2 (M) x 4 (N)
    const int q = lane >> 4, ln = lane & 15;
    const int col0 = blockIdx.x * 256;
    const int row0 = blockIdx.y * 256;

    const char* Ab = (const char*)A + (size_t)row0 * KB;
    const char* Bb = (const char*)B + (size_t)col0 * KB;

    // one chunk = 64 rows x 128 B; each wave DMAs 1 KiB (8 rows), dest wave-uniform+linear,
    // source column pre-swizzled so LDS contents match the swizzled read layout.
    auto stage_chunk = [&](const char* g, int fr, int kt, char* ldsbase) {
        const int rr = tid >> 3;
        const int cb = (tid & 7) << 4;
        const char* src = g + (size_t)(fr + rr) * KB + (size_t)kt * 128 + (cb ^ ((rr & 7) << 4));
        char* dst = ldsbase + ((tid >> 6) << 10);
        __builtin_amdgcn_global_load_lds((gvoid_t*)src, (lvoid_t*)dst, 16, 0, 0);
    };
    auto stageA2 = [&](int b, int t, int h) {     // h=0: rows 0-63 & 128-191; h=1: 64-127 & 192-255
        stage_chunk(Ab, h * 64,       t, (char*)&sA[b][0] + (size_t)(h * 64) * 128);
        stage_chunk(Ab, 128 + h * 64, t, (char*)&sA[b][0] + (size_t)(128 + h * 64) * 128);
    };
    auto stageB2 = [&](int b, int t, int h) {     // h: rows h*128 .. h*128+127
        stage_chunk(Bb, h * 128,      t, (char*)&sB[b][0] + (size_t)(h * 128) * 128);
        stage_chunk(Bb, h * 128 + 64, t, (char*)&sB[b][0] + (size_t)(h * 128 + 64) * 128);
    };
    auto readA = [&](int b, int mf, int ks) -> f16x8 {
        const int r = wm * 128 + mf * 16 + ln;
        return *(const f16x8*)((const char*)&sA[b][0] + r * 128 + ((ks * 64 + q * 16) ^ ((r & 7) << 4)));
    };
    auto readB = [&](int b, int nt, int ks) -> f16x8 {
        const int r = wn * 64 + nt * 16 + ln;
        return *(const f16x8*)((const char*)&sB[b][0] + r * 128 + ((ks * 64 + q * 16) ^ ((r & 7) << 4)));
    };

    // prologue: tile0 fully (4 half-tiles) + tile1 minus its AH1 (3 half-tiles) = 14 loads/wave
    stageB2(0, 0, 0); stageB2(0, 0, 1); stageA2(0, 0, 0); stageA2(0, 0, 1);
    stageB2(1, 1, 0); stageB2(1, 1, 1); stageA2(1, 1, 0);

    f32x4 acc[8][4];
    const f32x4 z4 = {0.f, 0.f, 0.f, 0.f};
#pragma unroll
    for (int mf = 0; mf < 8; ++mf)
#pragma unroll
        for (int nt = 0; nt < 4; ++nt) acc[mf][nt] = z4;

    asm volatile("s_waitcnt vmcnt(6)" ::: "memory");   // tile0's 8 loads retired
    asm volatile("s_barrier" ::: "memory");

    f16x8 af[2][2];
    f16x8 bf[4][2];

#pragma unroll 1
    for (int it = 0; it < 24; ++it) {
        const int t0 = it * 2;
        const bool notlast = (it != 23);
        // phases 0-3: compute tile t0 (buf0); phases 4-7: compute tile t0+1 (buf1).
        // staging ledger (overwrite-safe; verified): p0 AH1(t0+1)->buf1, p1/p2 BH0/BH1(t0+2)->buf0,
        // p3 AH0(t0+2)->buf0 +gate, p4 AH1(t0+2)->buf0, p5/p6 BH0/BH1(t0+3)->buf1,
        // p7 AH0(t0+3)->buf1 +gate. Gates wait the 4 oldest of 7 in-flight half-tiles: vmcnt(6).
        PHASE(0, 0, (stageA2(1, t0 + 1, 1)), 0);
        PHASE(0, 1, (notlast ? stageB2(0, t0 + 2, 0) : (void)0), 0);
        PHASE(0, 2, (notlast ? stageB2(0, t0 + 2, 1) : (void)0), 0);
        PHASE(0, 3, (notlast ? stageA2(0, t0 + 2, 0) : (void)0), 1);
        PHASE(1, 0, (notlast ? stageA2(0, t0 + 2, 1) : (void)0), 0);
        PHASE(1, 1, (notlast ? stageB2(1, t0 + 3, 0) : (void)0), 0);
        PHASE(1, 2, (notlast ? stageB2(1, t0 + 3, 1) : (void)0), 0);
        PHASE(1, 3, (notlast ? stageA2(1, t0 + 3, 0) : (void)0), 1);
    }

    // epilogue: C/D layout col=lane&15, row=(lane>>4)*4+reg; scatter to m[(bbl*16+h)][t][256]
#pragma unroll
    for (int nt = 0; nt < 4; ++nt) {
        const int c = col0 + wn * 64 + nt * 16 + ln;
        const float bv = bias[c];
        const int h = c >> 8, e = c & 255;
#pragma unroll
        for (int mf = 0; mf < 8; ++mf) {
#pragma unroll
            for (int r = 0; r < 4; ++r) {
                const int row = row0 + wm * 128 + mf * 16 + q * 4 + r;
                const int bbl = row >> 11, t = row & 2047;
                Mout[((size_t)(bbl * 16 + h) * Tdim + t) * 256 + e] = acc[mf][nt][r] + bv;
            }
        }
    }
}

// ---------------- Stage A (MFMA chain): per-chunk products, one wave per (seq,c) ----------
__global__ __launch_bounds__(256) void stageA_mfma(const float* __restrict__ m,
                                                   float* __restrict__ q, int SS)
{
    const int tid = threadIdx.x;
    const int wave = tid >> 6, lane = tid & 63;
    const int qd = lane >> 4, ln = lane & 15;
    const int chain = blockIdx.x * 4 + wave;
    const int seq = chain >> 6, c = chain & (Cn - 1);
    const float* mp = m + ((size_t)seq * Tdim + c * Ln) * 256;

    float vlr[4], vrl[4];                 // running products, fp32, B/D layout
#pragma unroll
    for (int r = 0; r < 4; ++r) {
        const float iv = (qd * 4 + r == ln) ? 1.0f : 0.0f;
        vlr[r] = iv; vrl[r] = iv;
    }

    for (int s = 0; s < Ln; ++s) {
        const float* Ms = mp + s * 256;
        const float4 arow = *(const float4*)(Ms + ln * 16 + qd * 4);  // M[ln][4qd..+3]
        float acol[4];
#pragma unroll
        for (int i = 0; i < 4; ++i) acol[i] = Ms[(4 * qd + i) * 16 + ln]; // M[4qd+i][ln]

        float f2 = arow.x*arow.x + arow.y*arow.y + arow.z*arow.z + arow.w*arow.w;
#pragma unroll
        for (int off = 1; off < 64; off <<= 1) f2 += __shfl_xor(f2, off);
        const float sm = 4.0f * rsqrtf(f2 + 1e-12f);

        f16x4 mhr, mlr2, mhc, mlc;
        const float ar[4] = {arow.x * sm, arow.y * sm, arow.z * sm, arow.w * sm};
#pragma unroll
        for (int i = 0; i < 4; ++i) {
            _Float16 h = (_Float16)ar[i];
            mhr[i] = h; mlr2[i] = (_Float16)((ar[i] - (float)h) * 1024.0f);
            const float v = acol[i] * sm;
            h = (_Float16)v;
            mhc[i] = h; mlc[i] = (_Float16)((v - (float)h) * 1024.0f);
        }
        f16x4 qh1, ql1, qh2, ql2;
#pragma unroll
        for (int r = 0; r < 4; ++r) {
            _Float16 h = (_Float16)vlr[r];
            qh1[r] = h; ql1[r] = (_Float16)((vlr[r] - (float)h) * 1024.0f);
            h = (_Float16)vrl[r];
            qh2[r] = h; ql2[r] = (_Float16)((vrl[r] - (float)h) * 1024.0f);
        }
        f32x4 a1 = {0.f,0.f,0.f,0.f}, a2 = {0.f,0.f,0.f,0.f};
        f32x4 b1 = {0.f,0.f,0.f,0.f}, b2 = {0.f,0.f,0.f,0.f};
        a1 = __builtin_amdgcn_mfma_f32_16x16x16f16(mhr,  qh1, a1, 0, 0, 0);
        a2 = __builtin_amdgcn_mfma_f32_16x16x16f16(mhr,  ql1, a2, 0, 0, 0);
        a2 = __builtin_amdgcn_mfma_f32_16x16x16f16(mlr2, qh1, a2, 0, 0, 0);
        b1 = __builtin_amdgcn_mfma_f32_16x16x16f16(mhc,  qh2, b1, 0, 0, 0);
        b2 = __builtin_amdgcn_mfma_f32_16x16x16f16(mhc,  ql2, b2, 0, 0, 0);
        b2 = __builtin_amdgcn_mfma_f32_16x16x16f16(mlc,  qh2, b2, 0, 0, 0);

        float mx1 = 0.f, mx2 = 0.f;
#pragma unroll
        for (int r = 0; r < 4; ++r) {
            vlr[r] = a1[r] + a2[r] * (1.0f / 1024.0f);
            vrl[r] = b1[r] + b2[r] * (1.0f / 1024.0f);
            mx1 = fmaxf(mx1, fabsf(vlr[r]));
            mx2 = fmaxf(mx2, fabsf(vrl[r]));
        }
#pragma unroll
        for (int off = 1; off < 64; off <<= 1) {
            mx1 = fmaxf(mx1, __shfl_xor(mx1, off));
            mx2 = fmaxf(mx2, __shfl_xor(mx2, off));
        }
        const float i1 = 1.0f / (mx1 + 1e-30f);
        const float i2 = 1.0f / (mx2 + 1e-30f);
#pragma unroll
        for (int r = 0; r < 4; ++r) { vlr[r] *= i1; vrl[r] *= i2; }
    }

    float ss = 0.f, st = 0.f;
#pragma unroll
    for (int r = 0; r < 4; ++r) { ss += vlr[r]*vlr[r]; st += vrl[r]*vrl[r]; }
#pragma unroll
    for (int off = 1; off < 64; off <<= 1) { ss += __shfl_xor(ss, off); st += __shfl_xor(st, off); }
    const float sl = 1.0f / (sqrtf(ss) + 1e-30f);
    const float sr = 1.0f / (sqrtf(st) + 1e-30f);
    float* qlr_out = q + ((size_t)seq * Cn + c) * 256;
    float* qrl_out = q + ((size_t)(SS + seq) * Cn + c) * 256;
#pragma unroll
    for (int r = 0; r < 4; ++r)
        qlr_out[(qd * 4 + r) * 16 + ln] = vlr[r] * sl;
    float4 qv; qv.x = vrl[0]*sr; qv.y = vrl[1]*sr; qv.z = vrl[2]*sr; qv.w = vrl[3]*sr;
    *(float4*)(qrl_out + ln * 16 + qd * 4) = qv;
}

// ---------------- Stage B: cross-chunk vector propagation --------------------------------
__global__ __launch_bounds__(64) void stageB_kernel(const float* __restrict__ q,
                                                    float* __restrict__ vs, int SS)
{
    const int lane = threadIdx.x & 63;
    const int i = lane & 15;
    const int chain = blockIdx.x;
    const int dir = (chain >= SS) ? 1 : 0;
    const int seq = chain - dir * SS;
    const float* qb = q + (size_t)(dir * SS + seq) * Cn * 256;
    float* vb = vs + (size_t)(dir * SS + seq) * Cn * 16;

    float myw = (i == 0) ? 1.0f : 0.0f;
    float wv[16];
#pragma unroll
    for (int k2 = 0; k2 < 16; ++k2) wv[k2] = (k2 == 0) ? 1.0f : 0.0f;

    for (int s = 0; s < Cn; ++s) {
        const int cc = dir ? (Cn - 1 - s) : s;
        vb[cc * 16 + i] = myw;
        const float* Qp = qb + (size_t)cc * 256 + i * 16;
        const float4 q0 = *(const float4*)(Qp + 0);
        const float4 q1 = *(const float4*)(Qp + 4);
        const float4 q2 = *(const float4*)(Qp + 8);
        const float4 q3 = *(const float4*)(Qp + 12);
        float nv = q0.x*wv[0] + q0.y*wv[1] + q0.z*wv[2] + q0.w*wv[3]
                 + q1.x*wv[4] + q1.y*wv[5] + q1.z*wv[6] + q1.w*wv[7]
                 + q2.x*wv[8] + q2.y*wv[9] + q2.z*wv[10] + q2.w*wv[11]
                 + q3.x*wv[12] + q3.y*wv[13] + q3.z*wv[14] + q3.w*wv[15];
        float s2 = nv * nv;
        s2 += __shfl_xor(s2, 1); s2 += __shfl_xor(s2, 2);
        s2 += __shfl_xor(s2, 4); s2 += __shfl_xor(s2, 8);
        const float wn = nv / (sqrtf(s2) + 1e-20f);
        myw = wn;
#pragma unroll
        for (int k2 = 0; k2 < 16; ++k2) wv[k2] = __shfl(wn, (lane & 48) | k2);
    }
}

// ---------------- Stage C: per-step history, LDS broadcast, f16 x output ------------------
__global__ __launch_bounds__(256) void stageC_kernel(const float* __restrict__ m,
                                                     const float* __restrict__ vs,
                                                     _Float16* __restrict__ x, int SS)
{
    __shared__ float vbuf[16][16];
    const int tid = threadIdx.x;
    const int lane = tid & 63;
    const int j = lane & 15;
    const int grp = tid >> 4;
    const int chain = blockIdx.x * 16 + grp;
    const int dir = chain & 1;
    const int sc = chain >> 1;
    const int c = sc & (Cn - 1), seq = sc >> 6;
    const int bbl = seq >> 4, h = seq & 15;

    vbuf[grp][j] = vs[((size_t)(dir * SS + seq) * Cn + c) * 16 + j];

    const int t0 = c * Ln;
    for (int s = 0; s < Ln; ++s) {
        const int t = dir ? (t0 + Ln - 1 - s) : (t0 + s);
        const float* Mp = m + ((size_t)seq * Tdim + t) * 256 + j * 16;
        const float4 r0 = *(const float4*)(Mp + 0);
        const float4 r1 = *(const float4*)(Mp + 4);
        const float4 r2 = *(const float4*)(Mp + 8);
        const float4 r3 = *(const float4*)(Mp + 12);
        const float4 w0 = *(const float4*)&vbuf[grp][0];
        const float4 w1 = *(const float4*)&vbuf[grp][4];
        const float4 w2 = *(const float4*)&vbuf[grp][8];
        const float4 w3 = *(const float4*)&vbuf[grp][12];
        float nv = r0.x*w0.x + r0.y*w0.y + r0.z*w0.z + r0.w*w0.w
                 + r1.x*w1.x + r1.y*w1.y + r1.z*w1.z + r1.w*w1.w
                 + r2.x*w2.x + r2.y*w2.y + r2.z*w2.z + r2.w*w2.w
                 + r3.x*w3.x + r3.y*w3.y + r3.z*w3.z + r3.w*w3.w;
        float s2 = nv * nv;
        s2 += __shfl_xor(s2, 1); s2 += __shfl_xor(s2, 2);
        s2 += __shfl_xor(s2, 4); s2 += __shfl_xor(s2, 8);
        const float vn = nv / (sqrtf(s2) + 1e-6f);
        x[(((size_t)bbl * Tdim + t) * NHd + h) * 32 + dir * 16 + j] = (_Float16)vn;
        vbuf[grp][j] = vn;
    }
}

// ---------------- GEMM2 (f16 MFMA): out = gelu(x @ W_out + b_out) -------------------------
__global__ __launch_bounds__(256) void gemm2_f16(const _Float16* __restrict__ A,
                                                 const _Float16* __restrict__ BT,
                                                 const float* __restrict__ bias,
                                                 float* __restrict__ out, int row0)
{
    __shared__ _Float16 Al[128 * LSTR];
    __shared__ _Float16 Bl[128 * LSTR];
    const int tid = threadIdx.x;
    const int wave = tid >> 6, lane = tid & 63;
    const int wm = wave & 1, wn = wave >> 1;
    const int qd = lane >> 4, ln = lane & 15;
    const int r0 = blockIdx.y * 128;
    const int c0 = blockIdx.x * 128;

    f32x4 acc[4][4] = {{{0.f,0.f,0.f,0.f}}};

    const int sr = tid >> 2, sc = tid & 3;
    const _Float16* Ag = A  + (size_t)(r0 + sr) * 512 + sc * 8;
    const _Float16* Bg = BT + (size_t)(c0 + sr) * 512 + sc * 8;
    _Float16* Alw = &Al[sr * LSTR + sc * 8];
    _Float16* Blw = &Bl[sr * LSTR + sc * 8];

    for (int k0 = 0; k0 < 512; k0 += 32) {
        const f16x8 a0 = *(const f16x8*)(Ag + k0);
        const f16x8 a1 = *(const f16x8*)(Ag + (size_t)64 * 512 + k0);
        const f16x8 b0 = *(const f16x8*)(Bg + k0);
        const f16x8 b1 = *(const f16x8*)(Bg + (size_t)64 * 512 + k0);
        __syncthreads();
        *(f16x8*)(Alw)             = a0;
        *(f16x8*)(Alw + 64 * LSTR) = a1;
        *(f16x8*)(Blw)             = b0;
        *(f16x8*)(Blw + 64 * LSTR) = b1;
        __syncthreads();
        f16x8 af[4], bfr[4];
#pragma unroll
        for (int mt = 0; mt < 4; ++mt)
            af[mt] = *(const f16x8*)&Al[(wm * 64 + mt * 16 + ln) * LSTR + qd * 8];
#pragma unroll
        for (int nt = 0; nt < 4; ++nt)
            bfr[nt] = *(const f16x8*)&Bl[(wn * 64 + nt * 16 + ln) * LSTR + qd * 8];
#pragma unroll
        for (int mt = 0; mt < 4; ++mt)
#pragma unroll
            for (int nt = 0; nt < 4; ++nt)
                acc[mt][nt] = __builtin_amdgcn_mfma_f32_16x16x32_f16(af[mt], bfr[nt], acc[mt][nt], 0, 0, 0);
    }
#pragma unroll
    for (int nt = 0; nt < 4; ++nt) {
        const int c = c0 + wn * 64 + nt * 16 + ln;
        const float bv = bias[c];
#pragma unroll
        for (int mt = 0; mt < 4; ++mt) {
#pragma unroll
            for (int r = 0; r < 4; ++r) {
                const int row = r0 + wm * 64 + mt * 16 + qd * 4 + r;
                float v = acc[mt][nt][r] + bv;
                v = 0.5f * v * (1.0f + erff(v * 0.70710678118654752f));
                out[(size_t)(row0 + row) * 1024 + c] = v;
            }
        }
    }
}

extern "C" void kernel_launch(void* const* d_in, const int* in_sizes, int n_in,
                              void* d_out, int out_size, void* d_ws, size_t ws_size,
                              hipStream_t stream)
{
    const float* hs    = (const float*)d_in[0];
    const float* W_mat = (const float*)d_in[1];
    const float* b_mat = (const float*)d_in[2];
    const float* W_out = (const float*)d_in[3];
    const float* b_out = (const float*)d_in[4];
    float* out = (float*)d_out;

    // layout: W2T(1M) Bcat(24M) | m: nbb*32M | qx: nbb*2M (q fp32 / x f16 aliased) |
    //         Acat: nbb*12M | vs: nbb*128K
    const size_t per_bb = (32ull << 20) + (2ull << 20) + (12ull << 20) + (128ull << 10);
    const size_t wbase  = 25ull << 20;
    int nbb = 8;
    while (nbb > 1 && ws_size < wbase + (size_t)nbb * per_bb) nbb >>= 1;

    char* base = (char*)d_ws;
    _Float16* W2T = (_Float16*)base;
    _Float16* Bc  = (_Float16*)(base + (1ull << 20));
    size_t off = wbase;
    float* m  = (float*)(base + off);  off += (size_t)nbb * (32ull << 20);
    float* qx = (float*)(base + off);  off += (size_t)nbb * (2ull << 20);
    _Float16* Ac = (_Float16*)(base + off); off += (size_t)nbb * (12ull << 20);
    float* vs = (float*)(base + off);

    conv_B_kernel<<<dim3(128, 32), 256, 0, stream>>>(W_mat, Bc);
    conv_W2T_kernel<<<dim3(32, 16), 256, 0, stream>>>(W_out, W2T);

    for (int bb0 = 0; bb0 < 8; bb0 += nbb) {
        const int row0 = bb0 * Tdim;
        const int SS = nbb * 16;
        conv_A_kernel<<<nbb * 1024, 256, 0, stream>>>(hs + (size_t)row0 * HIDd, Ac);
        gemm1_8ph<<<dim3(16, nbb * 8), 512, 0, stream>>>(Ac, Bc, b_mat, m);
        stageA_mfma<<<nbb * 256, 256, 0, stream>>>(m, qx, SS);
        stageB_kernel<<<nbb * 32, 64, 0, stream>>>(qx, vs, SS);
        stageC_kernel<<<nbb * 128, 256, 0, stream>>>(m, vs, (_Float16*)qx, SS);
        gemm2_f16<<<dim3(8, nbb * 16), 256, 0, stream>>>((_Float16*)qx, W2T, b_out, out, row0);
    }
}